// Round 7
// baseline (87.169 us; speedup 1.0000x reference)
//
#include <hip/hip_runtime.h>

// FourierFilter2D: out[b,h,w,f] = Re( sum_c x[b,h,w,c] * W[c,h,w,f] ) + b_re[f]
// B=8, H=64, W=64, C=64, F=64. Output: [B][H][W][F] float32, REAL part only
// (harness casts the complex64 reference with astype(float32) — verified r6).
//
// r6 post-mortem: passed at 36.6us but latency/issue-bound (VALUBusy 16%,
// hbm 17%, occupancy 38%). The LDS broadcast path (8192 ds_read_b64/CU
// ~14-20us of LDS-pipe time + lgkmcnt serialization) was the dominant cost.
// This version: NO LDS. x[b][hw][c] is wave-uniform -> force hw uniform with
// readfirstlane so the compiler emits scalar loads (s_load_dwordx4 over
// contiguous c), feeding v_fma's SGPR operand slot. W stays per-lane
// coalesced dword streams (lane = f, 256B/wave/load), unroll 4.

constexpr int B  = 8;
constexpr int Hh = 64;
constexpr int Ww = 64;
constexpr int C  = 64;
constexpr int F  = 64;
constexpr int HW  = Hh * Ww;        // 4096
constexpr int HWC = HW * C;         // 262144
constexpr int HWF = HW * F;         // 262144
constexpr int WAVES_PER_BLOCK = 4;  // 256 threads

__global__ __launch_bounds__(256) void fourier_filter2d_kernel(
    const float* __restrict__ x_re, const float* __restrict__ x_im,
    const float* __restrict__ w_re, const float* __restrict__ w_im,
    const float* __restrict__ b_re,
    float* __restrict__ out)
{
    // Wave id is uniform across the wave; readfirstlane makes it PROVABLY
    // uniform so x_re/x_im addresses below scalarize to s_load.
    const int wid  = __builtin_amdgcn_readfirstlane((int)(threadIdx.x >> 6));
    const int lane = threadIdx.x & 63;
    const int hw   = blockIdx.x * WAVES_PER_BLOCK + wid; // 0..4095, uniform

    // Wave-uniform x pointers for this position (index with b*HWC + c).
    const float* __restrict__ xr = x_re + hw * C;
    const float* __restrict__ xi = x_im + hw * C;

    // Lane `lane` owns filter f = lane. W loads: 64 lanes x 4 B = 256 B contiguous.
    const float* __restrict__ wr = w_re + hw * F + lane;
    const float* __restrict__ wi = w_im + hw * F + lane;

    float accr[B];
    #pragma unroll
    for (int b = 0; b < B; ++b) accr[b] = 0.0f;

    #pragma unroll 4
    for (int c = 0; c < C; ++c) {
        const float wrv = wr[(size_t)c * HWF];
        const float wiv = wi[(size_t)c * HWF];
        #pragma unroll
        for (int b = 0; b < B; ++b) {
            // x values are wave-uniform (SGPR); one SGPR source per v_fma is legal.
            const float xrv = xr[b * HWC + c];
            const float xiv = xi[b * HWC + c];
            // Re((xr + i*xi) * (wr + i*wi)) = xr*wr - xi*wi
            accr[b] = fmaf(xrv, wrv, fmaf(-xiv, wiv, accr[b]));
        }
    }

    const float br = b_re[lane];

    #pragma unroll
    for (int b = 0; b < B; ++b)
        out[b * HWF + hw * F + lane] = accr[b] + br;
}

extern "C" void kernel_launch(void* const* d_in, const int* in_sizes, int n_in,
                              void* d_out, int out_size, void* d_ws, size_t ws_size,
                              hipStream_t stream) {
    const float* x_re = (const float*)d_in[0];
    const float* x_im = (const float*)d_in[1];
    const float* w_re = (const float*)d_in[2];
    const float* w_im = (const float*)d_in[3];
    const float* b_re = (const float*)d_in[4];
    float* out = (float*)d_out;

    const int blocks = HW / WAVES_PER_BLOCK; // 1024
    fourier_filter2d_kernel<<<blocks, 256, 0, stream>>>(
        x_re, x_im, w_re, w_im, b_re, out);
}

// Round 8
// 42.146 us; speedup vs baseline: 2.0683x; 2.0683x over previous
//
#include <hip/hip_runtime.h>

// FourierFilter2D: out[b,h,w,f] = Re( sum_c x[b,h,w,c] * W[c,h,w,f] ) + b_re[f]
// B=8, H=64, W=64, C=64, F=64. Output: [B][H][W][F] float32, REAL part only.
//
// r6 (LDS broadcast, 36.6us): LDS crossbar charges broadcasts per-lane ->
//   512 ds_read_b64 x 16 waves/CU ~ 20-27us of LDS-pipe time. Bound.
// r7 (s_load scalarization, 87us): SMEM latency serialization, VALUBusy 3.6%.
// This version: MFMA. The matrix engine does the X-broadcast internally.
// Per hw: [8 x 64c] . [64c x 64f] real-part GEMM = 16 x mfma_f32_16x16x32_bf16
// per wave. No LDS, no syncthreads. Inputs f32 -> bf16 (RNE); fp32 accumulate.
// Expected error ~1e-2 vs bf16-rounded ref (threshold 3.4e-2).
//
// Fragment layouts (m89-verified convention):
//   A: lane l holds A[l&15][(l>>4)*8 + j], j=0..7   (row = b, k = c)
//   B: lane l holds B[(l>>4)*8 + j][l&15]           (k = c, col = f%16)
//   D: lane l, reg r = D[(l>>4)*4 + r][l&15]        (row = b, col = f%16)

typedef float f32x4 __attribute__((ext_vector_type(4)));
typedef short bf16x8 __attribute__((ext_vector_type(8)));

constexpr int B  = 8;
constexpr int C  = 64;
constexpr int F  = 64;
constexpr int HW  = 4096;
constexpr int HWC = HW * C;         // 262144
constexpr int HWF = HW * F;         // 262144
constexpr int WAVES_PER_BLOCK = 4;  // 256 threads

static __device__ __forceinline__ short f2bf(float f) {
    union { float f; unsigned u; } v; v.f = f;
    unsigned u = v.u + 0x7FFFu + ((v.u >> 16) & 1u);   // round-to-nearest-even
    return (short)(u >> 16);
}

__global__ __launch_bounds__(256) void fourier_filter2d_kernel(
    const float* __restrict__ x_re, const float* __restrict__ x_im,
    const float* __restrict__ w_re, const float* __restrict__ w_im,
    const float* __restrict__ b_re,
    float* __restrict__ out)
{
    const int wid  = threadIdx.x >> 6;
    const int lane = threadIdx.x & 63;
    const int hw   = blockIdx.x * WAVES_PER_BLOCK + wid; // one (h,w) per wave
    const int quad = lane >> 4;   // k-octet group: k = quad*8 + j (+ 32*kstep)
    const int m    = lane & 15;   // A row (=b) / B,D col (=f within 16-tile)

    // ---- A fragments: X[b=m][c]. Rows 8..15 are zero (M=16 pad of B=8).
    // Clamped load (same cache lines as the valid lane) then select-zero.
    const bool aval = (m < 8);
    const int  mb   = m & 7;
    const float* __restrict__ pr = x_re + mb * HWC + hw * C + quad * 8;
    const float* __restrict__ pi = x_im + mb * HWC + hw * C + quad * 8;

    bf16x8 ar[2], ai[2];   // ai holds -x_im (Re = xr*wr - xi*wi)
    #pragma unroll
    for (int ks = 0; ks < 2; ++ks) {
        #pragma unroll
        for (int j = 0; j < 8; ++j) {
            const float vr = aval ?  pr[ks * 32 + j] : 0.0f;
            const float vi = aval ? -pi[ks * 32 + j] : 0.0f;
            ar[ks][j] = f2bf(vr);
            ai[ks][j] = f2bf(vi);
        }
    }

    // ---- B fragments streamed from W; 16 MFMAs into 4 accumulators.
    f32x4 acc[4];
    #pragma unroll
    for (int nt = 0; nt < 4; ++nt) acc[nt] = (f32x4){0.f, 0.f, 0.f, 0.f};

    // Base: c = quad*8, f = m. Offsets: + (ks*32 + j)*HWF + nt*16.
    const float* __restrict__ wrp = w_re + (quad * 8) * HWF + hw * F + m;
    const float* __restrict__ wip = w_im + (quad * 8) * HWF + hw * F + m;

    #pragma unroll
    for (int nt = 0; nt < 4; ++nt) {
        #pragma unroll
        for (int ks = 0; ks < 2; ++ks) {
            bf16x8 br, bi;
            #pragma unroll
            for (int j = 0; j < 8; ++j) {
                const int off = (ks * 32 + j) * HWF + nt * 16;
                br[j] = f2bf(wrp[off]);
                bi[j] = f2bf(wip[off]);
            }
            acc[nt] = __builtin_amdgcn_mfma_f32_16x16x32_bf16(ar[ks], br, acc[nt], 0, 0, 0);
            acc[nt] = __builtin_amdgcn_mfma_f32_16x16x32_bf16(ai[ks], bi, acc[nt], 0, 0, 0);
        }
    }

    // ---- Store: D row = quad*4 + r = b (valid rows 0..7 -> quad 0,1 only).
    if (quad < 2) {
        #pragma unroll
        for (int nt = 0; nt < 4; ++nt) {
            const int f = nt * 16 + m;
            const float bias = b_re[f];
            #pragma unroll
            for (int r = 0; r < 4; ++r) {
                const int b = quad * 4 + r;
                out[b * HWF + hw * F + f] = acc[nt][r] + bias;
            }
        }
    }
}

extern "C" void kernel_launch(void* const* d_in, const int* in_sizes, int n_in,
                              void* d_out, int out_size, void* d_ws, size_t ws_size,
                              hipStream_t stream) {
    const float* x_re = (const float*)d_in[0];
    const float* x_im = (const float*)d_in[1];
    const float* w_re = (const float*)d_in[2];
    const float* w_im = (const float*)d_in[3];
    const float* b_re = (const float*)d_in[4];
    float* out = (float*)d_out;

    const int blocks = HW / WAVES_PER_BLOCK; // 1024
    fourier_filter2d_kernel<<<blocks, 256, 0, stream>>>(
        x_re, x_im, w_re, w_im, b_re, out);
}